// Round 15
// baseline (48.919 us; speedup 1.0000x reference)
//
#include <hip/hip_runtime.h>

typedef __attribute__((ext_vector_type(4))) float f32x4;
typedef __attribute__((ext_vector_type(8))) _Float16 f16x8;
typedef __attribute__((ext_vector_type(4))) unsigned short u16x4;

#define NB 8
#define LLEN 512
#define DD 768
#define MW 12
#define HH 384
#define TT (NB * LLEN)      // 4096 tokens
#define SS (LLEN * MW)      // 6144 spans per batch
#define RB 528              // X rows per batch (513 used: t=-1..511, rest pad)
#define MX (NB * RB)        // 4224 X rows

#define BT 32               // tokens per window
#define BE 64               // e-slice per block
#define WR 48               // R-window rows (44 used)
#define PRF 68              // R-tile LDS pitch in f32 (272 B: 4-bank shift/row)

#define PREPX_BLOCKS ((MX * 192) / 256)   // 3168
#define PREPW_BLOCKS ((DD * 192) / 256)   // 576
#define PREP_BLOCKS (PREPX_BLOCKS + PREPW_BLOCKS)

// ---------- helpers ----------
__device__ __forceinline__ unsigned short f2h(float x) {
  _Float16 h = (_Float16)x;               // RNE
  return __builtin_bit_cast(unsigned short, h);
}
__device__ __forceinline__ void gload_lds16(const void* g, void* l) {
  __builtin_amdgcn_global_load_lds(
      (const __attribute__((address_space(1))) unsigned int*)g,
      (__attribute__((address_space(3))) unsigned int*)l, 16, 0, 0);
}

// ---------- prep ----------
// X[b*RB + t + 1][0:384]   = fwd[b][t]   (ss at t==-1, clamped past 511)
// X[b*RB + t + 1][384:768] = bwd[b][t+1] (es at t>=511)
// Wp[e][k] = fp16(W[e][k])
__global__ __launch_bounds__(256) void prep_k(const float* __restrict__ h,
                                              const float* __restrict__ W,
                                              const float* __restrict__ ss,
                                              const float* __restrict__ es,
                                              unsigned short* __restrict__ X,
                                              unsigned short* __restrict__ Wp) {
  int bid = blockIdx.x;
  if (bid < PREPX_BLOCKS) {
    int idx = bid * 256 + threadIdx.x;        // over MX*192 u16x4 chunks
    int r = idx / 192;
    int c = (idx - r * 192) * 4;
    int b = r / RB;
    int t = r - b * RB - 1;                   // -1..526
    const float* src;
    if (c < HH) {
      src = (t == -1) ? (ss + c) : (h + ((size_t)b * LLEN + min(t, LLEN - 1)) * DD + c);
    } else {
      src = (t >= LLEN - 1) ? (es + (c - HH))
                            : (h + ((size_t)b * LLEN + (t + 1)) * DD + c);
    }
    f32x4 f = *(const f32x4*)src;
    u16x4 v;
#pragma unroll
    for (int j = 0; j < 4; ++j) v[j] = f2h(f[j]);
    *(u16x4*)(X + (size_t)r * DD + c) = v;
  } else {
    int idx = (bid - PREPX_BLOCKS) * 256 + threadIdx.x;  // over DD*192 chunks
    int e = idx / 192;
    int c = (idx - e * 192) * 4;
    f32x4 f = *(const f32x4*)(W + (size_t)e * DD + c);
    u16x4 v;
#pragma unroll
    for (int j = 0; j < 4; ++j) v[j] = f2h(f[j]);
    *(u16x4*)(Wp + (size_t)e * DD + c) = v;
  }
}

// ---------- fused telescoped GEMM + assemble, 2-window pipeline ----------
// Block = (pair p, e-slice ec): tokens [T0, T0+64), e [E0, E0+64).
//   GEMM(w0);  { GEMM(w1) with 2 write-iters of w0 per kc-step };  write(w1).
// Stores issue fire-and-forget between staging and barrier -> the 151 MB
// output stream flows while MFMA runs (forced intra-block phase stagger).
// R tiles kept f32 in LDS (no fp16 R rounding). Grid 768 = 3 blocks/CU;
// bid%8 = p%8 -> a pair's 12 e-siblings share an XCD.
__global__ __launch_bounds__(256, 3) void fused_k(const unsigned short* __restrict__ X,
                                                  const unsigned short* __restrict__ Wp,
                                                  const int* __restrict__ span,
                                                  const float* __restrict__ bias,
                                                  float* __restrict__ out) {
  __shared__ char stg[6144 + 8192];        // As [48][128B] + Bs [64][128B]
  __shared__ float Rt0[WR * PRF];          // 13056 B, f32
  __shared__ float Rt1[WR * PRF];
  __shared__ int2 spans[2 * BT * MW];      // 6144 B

  const int bid = blockIdx.x;
  const int ec = bid >> 6;                 // 0..11
  const int p  = bid & 63;                 // pair id; bid%8 = p%8 (XCD)
  const int b  = p >> 3;
  const int T0 = (p & 7) * (2 * BT);
  const int E0 = ec * BE;

  const int tid = threadIdx.x;
  const int lane = tid & 63;
  const int wv = tid >> 6;                 // wave -> 16-col N slice
  const int l16 = lane & 15, l4 = lane >> 4;

  {
    const int2* sp = (const int2*)span + (size_t)b * SS + (size_t)T0 * MW;
    for (int s = tid; s < 2 * BT * MW; s += 256) spans[s] = sp[s];
  }

  char* As = stg;
  char* Bs = stg + 6144;
  const char* Xb = (const char*)X;
  const char* Wb = (const char*)Wp;
  const size_t xb0 = (size_t)b * RB + T0;  // window0 row0 (t = T0-1)
  const size_t xb1 = xb0 + BT;

  const int e4 = tid & 15;                 // f32x4 chunk within 64-e slice
  const int lw0 = tid >> 4;                // base token-width row (16/iter)
  const f32x4 bb = ((const f32x4*)bias)[(E0 >> 2) + e4];
  f32x4* outB = (f32x4*)out + ((size_t)b * SS + (size_t)T0 * MW) * (DD / 4) + (E0 >> 2);

#define STAGE(xbase, kc)                                                      \
  {                                                                           \
    { int o = tid * 16; int rr = o >> 7, cb = o & 127;                        \
      gload_lds16(Xb + (((xbase) + rr) * DD + (kc)) * 2 + cb, As + o); }      \
    if (tid < 128) { int o = 4096 + tid * 16; int rr = o >> 7, cb = o & 127;  \
      gload_lds16(Xb + (((xbase) + rr) * DD + (kc)) * 2 + cb, As + o); }      \
    _Pragma("unroll")                                                         \
    for (int r2 = 0; r2 < 2; ++r2) {                                          \
      int o = (r2 * 256 + tid) * 16; int rr = o >> 7, cb = o & 127;           \
      gload_lds16(Wb + ((size_t)(E0 + rr) * DD + (kc)) * 2 + cb, Bs + o);     \
    }                                                                         \
  }

#define COMPUTE(acc)                                                          \
  {                                                                           \
    f16x8 af[2][3], bf[2];                                                    \
    _Pragma("unroll")                                                         \
    for (int ks = 0; ks < 2; ++ks) {                                          \
      _Pragma("unroll")                                                       \
      for (int m = 0; m < 3; ++m)                                             \
        af[ks][m] = *(const f16x8*)(As + (m * 16 + l16) * 128 + ks * 64 + l4 * 16); \
      bf[ks] = *(const f16x8*)(Bs + (wv * 16 + l16) * 128 + ks * 64 + l4 * 16);     \
    }                                                                         \
    _Pragma("unroll")                                                         \
    for (int m = 0; m < 3; ++m) {                                             \
      acc[m] = __builtin_amdgcn_mfma_f32_16x16x32_f16(af[0][m], bf[0], acc[m], 0, 0, 0); \
      acc[m] = __builtin_amdgcn_mfma_f32_16x16x32_f16(af[1][m], bf[1], acc[m], 0, 0, 0); \
    }                                                                         \
  }

#define ACC2LDS(acc, Rt)                                                      \
  _Pragma("unroll")                                                           \
  for (int m = 0; m < 3; ++m) {                                               \
    int row = m * 16 + l4 * 4;                                                \
    _Pragma("unroll")                                                         \
    for (int r = 0; r < 4; ++r)                                               \
      (Rt)[(row + r) * PRF + wv * 16 + l16] = acc[m][r];                      \
  }

#define WITER(Rt, w, it)                                                      \
  {                                                                           \
    int lw = lw0 + (it) * 16;                                                 \
    int2 se = spans[(w) * BT * MW + lw];                                      \
    int tb = T0 + (w) * BT;                                                   \
    const f32x4* R4 = (const f32x4*)(Rt);                                     \
    f32x4 pe = R4[(se.y - tb + 1) * (PRF / 4) + e4];                          \
    f32x4 mq = R4[(se.x - tb) * (PRF / 4) + e4];                              \
    f32x4 rr;                                                                 \
    _Pragma("unroll")                                                         \
    for (int j = 0; j < 4; ++j) rr[j] = fmaxf(pe[j] - mq[j] + bb[j], 0.f);    \
    outB[((size_t)(w) * BT * MW + lw) * (DD / 4) + e4] = rr;                  \
  }

  // ---- GEMM w0 ----
  f32x4 acc0[3] = {};
  for (int ki = 0; ki < 12; ++ki) {
    STAGE(xb0, ki * 64);
    __syncthreads();
    COMPUTE(acc0);
    __syncthreads();
  }
  ACC2LDS(acc0, Rt0);
  __syncthreads();                         // Rt0 visible to all

  // ---- GEMM w1, write(w0) interleaved (stores drain under MFMA) ----
  f32x4 acc1[3] = {};
  for (int ki = 0; ki < 12; ++ki) {
    STAGE(xb1, ki * 64);
    WITER(Rt0, 0, 2 * ki);
    WITER(Rt0, 0, 2 * ki + 1);
    __syncthreads();
    COMPUTE(acc1);
    __syncthreads();
  }
  ACC2LDS(acc1, Rt1);
  __syncthreads();

  // ---- write w1 ----
#pragma unroll 4
  for (int it = 0; it < 24; ++it) WITER(Rt1, 1, it);

#undef STAGE
#undef COMPUTE
#undef ACC2LDS
#undef WITER
}

// ---------- naive fallback (only if ws too small) ----------
__global__ __launch_bounds__(256) void naive_k(const float* __restrict__ h,
                                               const int* __restrict__ span,
                                               const float* __restrict__ W,
                                               const float* __restrict__ bias,
                                               const float* __restrict__ ss,
                                               const float* __restrict__ es,
                                               float* __restrict__ out) {
  int bs = blockIdx.x;
  int b = bs / SS;
  int start = span[(size_t)bs * 2 + 0];
  int end   = span[(size_t)bs * 2 + 1];
  __shared__ float rep[DD];
  const float* hb = h + (size_t)b * LLEN * DD;
  for (int k = threadIdx.x; k < HH; k += blockDim.x) {
    float fs = (start == 0) ? ss[k] : hb[(size_t)(start - 1) * DD + k];
    rep[k] = hb[(size_t)end * DD + k] - fs;
    float bstart = (end + 1 >= LLEN) ? es[k] : hb[(size_t)(end + 1) * DD + HH + k];
    rep[HH + k] = bstart - hb[(size_t)start * DD + HH + k];
  }
  __syncthreads();
  for (int e = threadIdx.x; e < DD; e += blockDim.x) {
    const float* w = W + (size_t)e * DD;
    float acc = bias[e];
    for (int k = 0; k < DD; k += 4) {
      acc += rep[k] * w[k] + rep[k + 1] * w[k + 1] + rep[k + 2] * w[k + 2] + rep[k + 3] * w[k + 3];
    }
    out[(size_t)bs * DD + e] = fmaxf(acc, 0.f);
  }
}

extern "C" void kernel_launch(void* const* d_in, const int* in_sizes, int n_in,
                              void* d_out, int out_size, void* d_ws, size_t ws_size,
                              hipStream_t stream) {
  const float* h  = (const float*)d_in[0];
  const int* span = (const int*)d_in[1];
  const float* W  = (const float*)d_in[2];
  const float* bias = (const float*)d_in[3];
  const float* ss = (const float*)d_in[4];
  const float* es = (const float*)d_in[5];
  float* out = (float*)d_out;

  const size_t szX = (size_t)MX * DD * sizeof(unsigned short);    // 6.49 MB
  const size_t szW = (size_t)DD * DD * sizeof(unsigned short);    // 1.18 MB
  const size_t need = szX + szW;                                  // ~7.7 MB

  if (ws_size < need) {
    naive_k<<<NB * SS, 256, 0, stream>>>(h, span, W, bias, ss, es, out);
    return;
  }

  char* ws = (char*)d_ws;
  unsigned short* X  = (unsigned short*)ws;                // [MX][DD] fp16
  unsigned short* Wp = X + (size_t)MX * DD;                // [DD][DD] fp16

  prep_k<<<PREP_BLOCKS, 256, 0, stream>>>(h, W, ss, es, X, Wp);
  fused_k<<<768, 256, 0, stream>>>(X, Wp, span, bias, out);
}